// Round 1
// 110.556 us; speedup vs baseline: 1.0086x; 1.0086x over previous
//
#include <hip/hip_runtime.h>
#include <math.h>

#define NN 768
#define CC 256
#define TI 3     // rows per block (both kernels)
#define JC 256   // j columns per wave-group in k_attn2

__device__ __forceinline__ float leaky(float x) { return x >= 0.0f ? x : 0.2f * x; }

__device__ __forceinline__ float waveMax(float v) {
    #pragma unroll
    for (int o = 32; o > 0; o >>= 1) v = fmaxf(v, __shfl_xor(v, o, 64));
    return v;
}
__device__ __forceinline__ float waveSum(float v) {
    #pragma unroll
    for (int o = 32; o > 0; o >>= 1) v += __shfl_xor(v, o, 64);
    return v;
}

// Kernel 1: f = features @ FC; g[c][j] = w1*f[j][c]+b (transposed);
// D0/D1 = per-row linear-term dots; ut4[triple][c] = {w0*f_r0[c], w0*f_r1[c],
// w0*f_r2[c], 0.4*lin_w[c]}.  (Unchanged from the proven champion.)
__global__ __launch_bounds__(768) void k_prep(
    const float* __restrict__ features,
    const float* __restrict__ FC,
    const float* __restrict__ fc_w,
    const float* __restrict__ fc_b,
    const float* __restrict__ lin_w,
    float* __restrict__ f,
    float* __restrict__ g,
    float* __restrict__ D0,
    float* __restrict__ D1,
    float4* __restrict__ ut4)
{
    __shared__ float sA[TI * CC];
    __shared__ float sF[TI * CC];
    __shared__ float sredD[12], sredW[12];

    const int t  = threadIdx.x;
    const int r  = t >> 8;
    const int c  = t & 255;
    const int i0 = blockIdx.x * TI;

    sA[r * CC + c] = features[(i0 + r) * CC + c];
    __syncthreads();

    float a = 0.f;
    const float* fcp = FC + c;
    const float* ap  = sA + r * CC;
    #pragma unroll 8
    for (int k = 0; k < CC; ++k)
        a = fmaf(ap[k], fcp[k * CC], a);

    const float w1 = fc_w[1], b = fc_b[0];
    f[(i0 + r) * CC + c] = a;
    g[c * NN + i0 + r]   = fmaf(w1, a, b);
    sF[r * CC + c] = a;

    const float lw = lin_w[c];
    float dv = waveSum(lw * a);
    float wv = waveSum(lw);
    const int wid = t >> 6;
    if ((t & 63) == 0) { sredD[wid] = dv; sredW[wid] = wv; }
    __syncthreads();
    if (t < TI) {
        float D = sredD[t*4] + sredD[t*4+1] + sredD[t*4+2] + sredD[t*4+3];
        float W = sredW[t*4] + sredW[t*4+1] + sredW[t*4+2] + sredW[t*4+3];
        D0[i0 + t] = fc_w[0] * D;
        D1[i0 + t] = fmaf(w1, D, b * W);
    }
    if (t < CC) {
        const float w0 = fc_w[0];
        ut4[blockIdx.x * CC + t] = make_float4(w0 * sF[t],
                                               w0 * sF[CC + t],
                                               w0 * sF[2*CC + t],
                                               0.4f * lin_w[t]);
    }
}

// Kernel 2 (NEW structure): one block per row-triple, 256 blocks x 768 threads
// (12 waves = 3/SIMD, exactly 1 block/CU). Wave w -> (c-slice cs=w&3 of 64 c,
// j-block js=w>>2 of 256 j) for phase 1; FULL 768-wide softmax in LDS (no
// partials, no Mp/Lp); phase 3 wave owns j-slice of 64, lane owns c-quad;
// ELU + output written directly (k_comb and the hp round-trip eliminated).
// spart (4x3x768 f) and hpart (12x3x256 f) alias the same 36 KB LDS buffer.
__global__ __launch_bounds__(768) void k_attn2(
    const float* __restrict__ f,      // [N][C]
    const float* __restrict__ g,      // [C][N]
    const float4* __restrict__ ut4,   // [N/3][C]
    const float* __restrict__ D0,     // [N]
    const float* __restrict__ D1,     // [N]
    const float* __restrict__ coords, // [N][3]
    const float* __restrict__ sc_w,
    const float* __restrict__ sc_b,
    const float* __restrict__ lin_w,  // [C+3]
    const float* __restrict__ lin_b,
    float* __restrict__ out)          // [N][C]
{
    __shared__ float4 su4[CC];          // 4 KB: staged u for this row-triple
    __shared__ float  sbig[4 * TI * NN]; // 36 KB: spart[4][TI][NN] / hpart[12][TI][CC]
    __shared__ float4 pp[NN];           // 12 KB: {e0,e1,e2,-} per j
    __shared__ float4 sredm4[12];
    __shared__ float4 sreds4[12];

    const int t    = threadIdx.x;       // 0..767
    const int it   = blockIdx.x;        // row-triple
    const int i0   = it * TI;
    const int w    = t >> 6;            // wave 0..11
    const int lane = t & 63;

    if (t < CC) su4[t] = ut4[(size_t)it * CC + t];
    __syncthreads();

    // ---- Phase 1: wave (cs, js): acc over c in [64cs,64cs+64) for j-quad
    //      js*256 + 4*lane ----
    const int cs = w & 3;
    const int js = w >> 2;
    const int jb = js * JC;

    float4 a0 = make_float4(0.f,0.f,0.f,0.f);
    float4 a1 = a0, a2 = a0;
    const float4* gq = (const float4*)g + (size_t)(cs << 6) * (NN/4) + (jb >> 2) + lane;
    const float4* su = su4 + (cs << 6);
    #pragma unroll 8
    for (int cc = 0; cc < 64; ++cc) {
        float4 gv = gq[cc * (NN/4)];   // coalesced 1KB/wave, L2
        float4 u  = su[cc];            // ds_read_b128 broadcast (conflict-free)
        a0.x = fmaf(u.w, fabsf(u.x + gv.x), a0.x);
        a0.y = fmaf(u.w, fabsf(u.x + gv.y), a0.y);
        a0.z = fmaf(u.w, fabsf(u.x + gv.z), a0.z);
        a0.w = fmaf(u.w, fabsf(u.x + gv.w), a0.w);
        a1.x = fmaf(u.w, fabsf(u.y + gv.x), a1.x);
        a1.y = fmaf(u.w, fabsf(u.y + gv.y), a1.y);
        a1.z = fmaf(u.w, fabsf(u.y + gv.z), a1.z);
        a1.w = fmaf(u.w, fabsf(u.y + gv.w), a1.w);
        a2.x = fmaf(u.w, fabsf(u.z + gv.x), a2.x);
        a2.y = fmaf(u.w, fabsf(u.z + gv.y), a2.y);
        a2.z = fmaf(u.w, fabsf(u.z + gv.z), a2.z);
        a2.w = fmaf(u.w, fabsf(u.z + gv.w), a2.w);
    }
    *(float4*)&sbig[(cs*TI + 0)*NN + jb + 4*lane] = a0;
    *(float4*)&sbig[(cs*TI + 1)*NN + jb + 4*lane] = a1;
    *(float4*)&sbig[(cs*TI + 2)*NN + jb + 4*lane] = a2;
    __syncthreads();

    // ---- Tail: thread t owns j = t; reduce the 4 c-slice partials ----
    const int j = t;
    float accs[TI];
    #pragma unroll
    for (int rr = 0; rr < TI; ++rr)
        accs[rr] = sbig[(0*TI + rr)*NN + j] + sbig[(1*TI + rr)*NN + j]
                 + sbig[(2*TI + rr)*NN + j] + sbig[(3*TI + rr)*NN + j];

    const float sw0 = sc_w[0], sw1 = sc_w[1], sb = sc_b[0], lb = lin_b[0];
    const float lw30 = lin_w[CC], lw31 = lin_w[CC+1], lw32 = lin_w[CC+2];
    const float cj0 = fmaf(sw1, coords[j*3+0], sb);
    const float cj1 = fmaf(sw1, coords[j*3+1], sb);
    const float cj2 = fmaf(sw1, coords[j*3+2], sb);
    const float d1  = D1[j];
    float scv[TI];
    #pragma unroll
    for (int rr = 0; rr < TI; ++rr) {
        const int i = i0 + rr;
        float sd = lw30 * leaky(fmaf(sw0, coords[i*3+0], cj0))
                 + lw31 * leaky(fmaf(sw0, coords[i*3+1], cj1))
                 + lw32 * leaky(fmaf(sw0, coords[i*3+2], cj2));
        scv[rr] = leaky(accs[rr] + sd + 0.6f * (D0[i] + d1) + lb);
    }

    // ---- Full softmax over all 768 j (12-wave reduction) ----
    {
        float v0 = waveMax(scv[0]);
        float v1 = waveMax(scv[1]);
        float v2 = waveMax(scv[2]);
        if (lane == 0) sredm4[w] = make_float4(v0, v1, v2, 0.f);
    }
    __syncthreads();
    float m0 = -1e30f, m1 = -1e30f, m2 = -1e30f;
    #pragma unroll
    for (int k = 0; k < 12; ++k) {
        float4 x = sredm4[k];
        m0 = fmaxf(m0, x.x); m1 = fmaxf(m1, x.y); m2 = fmaxf(m2, x.z);
    }
    float e0 = __expf(scv[0] - m0);
    float e1 = __expf(scv[1] - m1);
    float e2 = __expf(scv[2] - m2);
    pp[t] = make_float4(e0, e1, e2, 0.f);
    {
        float v0 = waveSum(e0);
        float v1 = waveSum(e1);
        float v2 = waveSum(e2);
        if (lane == 0) sreds4[w] = make_float4(v0, v1, v2, 0.f);
    }
    __syncthreads();   // publishes pp + sreds4; also fences last sbig reads
    float l0 = 0.f, l1 = 0.f, l2 = 0.f;
    #pragma unroll
    for (int k = 0; k < 12; ++k) {
        float4 x = sreds4[k];
        l0 += x.x; l1 += x.y; l2 += x.z;
    }
    const float inv0 = 1.f / l0, inv1 = 1.f / l1, inv2 = 1.f / l2;

    // ---- Phase 3: wave w owns j-slice [64w,64w+64); lane owns 4 channels ----
    float4 h0 = make_float4(0.f,0.f,0.f,0.f);
    float4 h1 = h0, h2 = h0;
    const float4* f4 = (const float4*)f;   // [N][64] float4
    const int jsl = w * 64;
    #pragma unroll 4
    for (int jx = 0; jx < 64; ++jx) {
        const int jl = jsl + jx;
        float4 fv = f4[(size_t)jl * 64 + lane];  // coalesced 1KB/wave
        float4 e  = pp[jl];                      // ds_read_b128 broadcast
        h0.x = fmaf(e.x, fv.x, h0.x); h0.y = fmaf(e.x, fv.y, h0.y);
        h0.z = fmaf(e.x, fv.z, h0.z); h0.w = fmaf(e.x, fv.w, h0.w);
        h1.x = fmaf(e.y, fv.x, h1.x); h1.y = fmaf(e.y, fv.y, h1.y);
        h1.z = fmaf(e.y, fv.z, h1.z); h1.w = fmaf(e.y, fv.w, h1.w);
        h2.x = fmaf(e.z, fv.x, h2.x); h2.y = fmaf(e.z, fv.y, h2.y);
        h2.z = fmaf(e.z, fv.z, h2.z); h2.w = fmaf(e.z, fv.w, h2.w);
    }
    // hpart[w][rr][c] aliases sbig (safe: 2 barriers since last spart read)
    *(float4*)&sbig[(w*TI + 0)*CC + 4*lane] = h0;
    *(float4*)&sbig[(w*TI + 1)*CC + 4*lane] = h1;
    *(float4*)&sbig[(w*TI + 2)*CC + 4*lane] = h2;
    __syncthreads();

    // ---- Epilogue: reduce 12 wave-partials, normalize, ELU, store ----
    const int rr = t >> 8;      // 0..2
    const int c  = t & 255;
    float h = 0.f;
    #pragma unroll
    for (int k = 0; k < 12; ++k) h += sbig[(k*TI + rr)*CC + c];
    const float inv = (rr == 0) ? inv0 : (rr == 1) ? inv1 : inv2;
    float v = h * inv;
    out[(i0 + rr)*CC + c] = (v > 0.f) ? v : (__expf(v) - 1.0f);
}

extern "C" void kernel_launch(void* const* d_in, const int* in_sizes, int n_in,
                              void* d_out, int out_size, void* d_ws, size_t ws_size,
                              hipStream_t stream) {
    const float* features = (const float*)d_in[0];
    const float* coords   = (const float*)d_in[1];
    // d_in[2] = adj, unused by forward
    const float* FC       = (const float*)d_in[3];
    const float* fc_w     = (const float*)d_in[4];
    const float* fc_b     = (const float*)d_in[5];
    const float* sc_w     = (const float*)d_in[6];
    const float* sc_b     = (const float*)d_in[7];
    const float* lin_w    = (const float*)d_in[8];
    const float* lin_b    = (const float*)d_in[9];
    float* out = (float*)d_out;

    // ws layout: ut4 first (guarantees 16B alignment), then fp32 arrays.
    float4* ut4 = (float4*)d_ws;            // (N/3)*C float4 = 1 MB
    float* f  = (float*)(ut4 + (NN/TI)*CC); // N*C
    float* g  = f  + NN*CC;                 // C*N
    float* D0 = g  + CC*NN;                 // N
    float* D1 = D0 + NN;                    // N

    k_prep<<<NN/TI, 768, 0, stream>>>(features, FC, fc_w, fc_b, lin_w, f, g, D0, D1, ut4);
    k_attn2<<<NN/TI, 768, 0, stream>>>(f, g, ut4, D0, D1, coords, sc_w, sc_b,
                                       lin_w, lin_b, out);
}